// Round 5
// baseline (470.973 us; speedup 1.0000x reference)
//
#include <hip/hip_runtime.h>
#include <hip/hip_bf16.h>

#define B_ 4
#define T_ 2048
#define C_ 1024
#define H_ 16
#define D_ 64
#define M_ (B_*T_)   // 8192

typedef unsigned short ushort;
typedef __attribute__((ext_vector_type(8))) short short8;
typedef __attribute__((ext_vector_type(8))) unsigned short ushort8;
typedef __attribute__((ext_vector_type(4))) float floatx4;
typedef __attribute__((ext_vector_type(4))) unsigned int uintx4;

static __device__ __forceinline__ float bf2f(ushort u) {
    unsigned int x = ((unsigned int)u) << 16;
    return __builtin_bit_cast(float, x);
}
static __device__ __forceinline__ ushort f2bf(float f) {
    unsigned int x = __builtin_bit_cast(unsigned int, f);
    unsigned int r = (x + 0x7fffu + ((x >> 16) & 1u)) >> 16;
    return (ushort)r;
}

typedef const __attribute__((address_space(1))) unsigned int gu32;
typedef __attribute__((address_space(3))) unsigned int lu32;
static __device__ __forceinline__ void glds16(const void* g, void* l) {
    __builtin_amdgcn_global_load_lds((gu32*)g, (lu32*)l, 16, 0, 0);
}

// ---------------- LayerNorm: fp32 in -> bf16 out ----------------
__global__ __launch_bounds__(256) void ln_kernel(
    const float* __restrict__ x, const float* __restrict__ g,
    const float* __restrict__ be, ushort* __restrict__ out)
{
    int row = blockIdx.x;
    int tid = threadIdx.x;
    const float* xr = x + (size_t)row * C_;
    float v[4];
    float s = 0.f, s2 = 0.f;
#pragma unroll
    for (int i = 0; i < 4; i++) {
        float t = xr[tid + i * 256];
        v[i] = t; s += t; s2 += t * t;
    }
#pragma unroll
    for (int off = 32; off; off >>= 1) {
        s  += __shfl_down(s, off);
        s2 += __shfl_down(s2, off);
    }
    __shared__ float rs[4], rs2[4];
    __shared__ float smu, srstd;
    int w = tid >> 6;
    if ((tid & 63) == 0) { rs[w] = s; rs2[w] = s2; }
    __syncthreads();
    if (tid == 0) {
        float ts  = rs[0] + rs[1] + rs[2] + rs[3];
        float ts2 = rs2[0] + rs2[1] + rs2[2] + rs2[3];
        float mu  = ts * (1.f / C_);
        float var = ts2 * (1.f / C_) - mu * mu;
        smu = mu; srstd = rsqrtf(var + 1e-5f);
    }
    __syncthreads();
    float mu = smu, r = srstd;
#pragma unroll
    for (int i = 0; i < 4; i++) {
        int c = tid + i * 256;
        out[(size_t)row * C_ + c] = f2bf((v[i] - mu) * r * g[c] + be[c]);
    }
}

// ------------- transpose + fp32->bf16 convert: in (R x Cn) -> out (Cn x R) -------------
__global__ __launch_bounds__(256) void transpose_conv(
    const float* __restrict__ in, ushort* __restrict__ out,
    int R, int Cn, long long in_bstride, long long out_bstride)
{
    __shared__ float tile[32][33];
    const float* ip = in + (size_t)blockIdx.z * in_bstride;
    ushort* op = out + (size_t)blockIdx.z * out_bstride;
    int tx = threadIdx.x;          // 32
    int ty = threadIdx.y;          // 8
    int c0 = blockIdx.x * 32, r0 = blockIdx.y * 32;
#pragma unroll
    for (int i = 0; i < 32; i += 8) {
        tile[ty + i][tx] = ip[(size_t)(r0 + ty + i) * Cn + c0 + tx];
    }
    __syncthreads();
#pragma unroll
    for (int i = 0; i < 32; i += 8) {
        int oc = c0 + ty + i;
        int orr = r0 + tx;
        op[(size_t)oc * R + orr] = f2bf(tile[tx][ty + i]);
    }
}

// ------------- V transpose: qkv V block -> VtG[(h*256 + 4*d + b)*2048 + t] -------------
__global__ __launch_bounds__(256) void vtrans_kernel(
    const ushort* __restrict__ qkv, ushort* __restrict__ VtG)
{
    int bh = blockIdx.y;
    int b = bh >> 4, h = bh & 15;
    int j0 = blockIdx.x * 64;
    int tid = threadIdx.x;
    __shared__ unsigned int X[64 * 33];
    const ushort* Vg = qkv + (size_t)(b * T_) * 3072 + 2048 + h * 64;
#pragma unroll
    for (int it = 0; it < 2; it++) {
        int j = (tid >> 3) + it * 32;
        int dp = (tid & 7) * 4;
        uintx4 val = *(const uintx4*)(Vg + (size_t)(j0 + j) * 3072 + dp * 2);
#pragma unroll
        for (int k = 0; k < 4; k++) X[j * 33 + dp + k] = val[k];
    }
    __syncthreads();
    int dp = tid >> 3, jc = tid & 7;
    unsigned int v[8];
#pragma unroll
    for (int jj = 0; jj < 8; jj++) v[jj] = X[(jc * 8 + jj) * 33 + dp];
    ushort8 lo, hi;
#pragma unroll
    for (int jj = 0; jj < 8; jj++) {
        lo[jj] = (ushort)(v[jj] & 0xffffu);
        hi[jj] = (ushort)(v[jj] >> 16);
    }
    size_t r0 = ((size_t)(h * 256 + 4 * (2 * dp) + b)) * T_ + j0 + jc * 8;
    size_t r1 = ((size_t)(h * 256 + 4 * (2 * dp + 1) + b)) * T_ + j0 + jc * 8;
    *(ushort8*)&VtG[r0] = lo;
    *(ushort8*)&VtG[r1] = hi;
}

// ---------------- bf16 MFMA GEMM: double-buffered, single barrier/K-step, XCD-swizzled 1D grid ----------------
// C(MxN) = A(MxK) @ Bt(NxK)^T [+bias][+resid][relu].  Grid = Mt*Nt blocks, Mt = M/128 (divisible by 8).
template<bool OUTBF16, bool BIAS, bool RELU, bool RESID>
__global__ __launch_bounds__(256, 2) void gemm_kernel(
    const ushort* __restrict__ A,
    const ushort* __restrict__ Bt,
    const float* __restrict__ bias,
    const float* __restrict__ resid,
    void* __restrict__ Cout,
    int Ndim, int K, int Nt)
{
    __shared__ ushort As[2][128 * 64];
    __shared__ ushort Bs[2][128 * 64];
    // XCD-affinity swizzle: xcd = bid&7; per-XCD contiguous m-slab, n fastest
    int bid = blockIdx.x;
    int xcd = bid & 7;
    int loc = bid >> 3;
    int m0 = (xcd * 8 + loc / Nt) * 128;   // Mt==64: 8 m-tiles per XCD
    int n0 = (loc % Nt) * 128;

    int tid = threadIdx.x;
    int wave = tid >> 6, lane = tid & 63;
    int quad = lane >> 4, l16 = lane & 15;
    int wm = (wave >> 1) * 64, wn = (wave & 1) * 64;
    floatx4 acc[4][4] = {};

    int lrow = lane >> 3;
    int lchunk = (lane & 7) ^ (lrow & 7);
    const ushort* Ab = A  + (size_t)m0 * K + lchunk * 8;
    const ushort* Bb = Bt + (size_t)n0 * K + lchunk * 8;

    int nK = K >> 6;
    // prologue: stage K-step 0 into buffer 0
#pragma unroll
    for (int it = 0; it < 4; it++) {
        int rb = wave * 32 + it * 8;
        int r  = rb + lrow;
        glds16(Ab + (size_t)r * K, &As[0][rb * 64]);
        glds16(Bb + (size_t)r * K, &Bs[0][rb * 64]);
    }

    for (int ki = 0; ki < nK; ki++) {
        int buf = ki & 1;
        __syncthreads();   // tile ki resident (vmcnt drain); prior reads of buf done
        if (ki + 1 < nK) {
            int kn = (ki + 1) * 64;
#pragma unroll
            for (int it = 0; it < 4; it++) {
                int rb = wave * 32 + it * 8;
                int r  = rb + lrow;
                glds16(Ab + (size_t)r * K + kn, &As[buf ^ 1][rb * 64]);
                glds16(Bb + (size_t)r * K + kn, &Bs[buf ^ 1][rb * 64]);
            }
        }
#pragma unroll
        for (int kk = 0; kk < 2; kk++) {
            short8 af[4], bfv[4];
            int c = kk * 4 + quad;
            int sw = (c ^ (l16 & 7)) * 8;
#pragma unroll
            for (int mi = 0; mi < 4; mi++)
                af[mi] = *(const short8*)&As[buf][(wm + mi * 16 + l16) * 64 + sw];
#pragma unroll
            for (int ni = 0; ni < 4; ni++)
                bfv[ni] = *(const short8*)&Bs[buf][(wn + ni * 16 + l16) * 64 + sw];
#pragma unroll
            for (int mi = 0; mi < 4; mi++)
#pragma unroll
                for (int ni = 0; ni < 4; ni++)
                    acc[mi][ni] = __builtin_amdgcn_mfma_f32_16x16x32_bf16(af[mi], bfv[ni], acc[mi][ni], 0, 0, 0);
        }
    }

    int r4 = quad * 4;
#pragma unroll
    for (int mi = 0; mi < 4; mi++) {
#pragma unroll
        for (int ni = 0; ni < 4; ni++) {
#pragma unroll
            for (int r = 0; r < 4; r++) {
                int gm = m0 + wm + mi * 16 + r4 + r;
                int gn = n0 + wn + ni * 16 + l16;
                float v = acc[mi][ni][r];
                if (BIAS)  v += bias[gn];
                if (RESID) v += resid[(size_t)gm * Ndim + gn];
                if (RELU)  v = fmaxf(v, 0.f);
                if (OUTBF16) ((ushort*)Cout)[(size_t)gm * Ndim + gn] = f2bf(v);
                else         ((float*)Cout)[(size_t)gm * Ndim + gn] = v;
            }
        }
    }
}

// ---------------- causal flash attention: XCD-swizzled, dbuf glds, static-max softmax ----------------
__global__ __launch_bounds__(256, 2) void attn_kernel(
    const ushort* __restrict__ qkv,
    const ushort* __restrict__ VtG,   // (h*256 + 4*d + b)*2048 + t
    ushort* __restrict__ attnb)
{
    const int LD = 3072;
    int bid = blockIdx.x;
    int bh = (bid & 7) * 8 + ((bid >> 3) & 7);
    int qt = 15 - (bid >> 6);
    int b = bh >> 4, h = bh & 15;
    int t0 = qt * 128;
    int tid = threadIdx.x;
    int wave = tid >> 6, lane = tid & 63;
    int quad = lane >> 4, l16 = lane & 15;

    __shared__ ushort Ks[2][64 * 64];
    __shared__ ushort Vt[2][64 * 64];
    __shared__ ushort Ps[4][32 * 72];

    const ushort* Qg = qkv + (size_t)(b * T_) * LD + h * 64;
    const ushort* Kg = Qg + 1024;
    const ushort* VtB = VtG + (size_t)(h * 256 + b) * T_;

    int qrow_base = t0 + wave * 32;
    int lrow = lane >> 3;
    int lchunk = (lane & 7) ^ (lrow & 7);

    short8 qa[2][2];
#pragma unroll
    for (int mt = 0; mt < 2; mt++) {
        const ushort* qp = Qg + (size_t)(qrow_base + mt * 16 + l16) * LD + quad * 8;
        ushort8 q0 = *(const ushort8*)qp;
        ushort8 q1 = *(const ushort8*)(qp + 32);
        ushort8 a0, a1;
#pragma unroll
        for (int d = 0; d < 8; d++) {
            a0[d] = f2bf(bf2f(q0[d]) * 0.03125f);
            a1[d] = f2bf(bf2f(q1[d]) * 0.03125f);
        }
        qa[mt][0] = __builtin_bit_cast(short8, a0);
        qa[mt][1] = __builtin_bit_cast(short8, a1);
    }

    float l_part[2][4];
    floatx4 o_acc[2][4];
#pragma unroll
    for (int mt = 0; mt < 2; mt++)
#pragma unroll
        for (int r = 0; r < 4; r++) {
            l_part[mt][r] = 0.f;
            o_acc[mt][r] = floatx4{0.f, 0.f, 0.f, 0.f};
        }

    int nIter = t0 / 64 + 2;

#pragma unroll
    for (int it = 0; it < 2; it++) {
        int rb = (wave * 2 + it) * 8;
        int r = rb + lrow;
        glds16(Kg  + (size_t)r * LD + lchunk * 8, &Ks[0][rb * 64]);
        glds16(VtB + (size_t)r * (4 * T_) + lchunk * 8, &Vt[0][rb * 64]);
    }

    for (int ii = 0; ii < nIter; ii++) {
        int s0 = ii * 64;
        int buf = ii & 1;
        __syncthreads();
        if (ii + 1 < nIter) {
            int sn = s0 + 64;
#pragma unroll
            for (int it = 0; it < 2; it++) {
                int rb = (wave * 2 + it) * 8;
                int r = rb + lrow;
                glds16(Kg  + (size_t)(sn + r) * LD + lchunk * 8, &Ks[buf ^ 1][rb * 64]);
                glds16(VtB + (size_t)r * (4 * T_) + sn + lchunk * 8, &Vt[buf ^ 1][rb * 64]);
            }
        }

        if (s0 <= qrow_base + 31) {
#pragma unroll
            for (int mt = 0; mt < 2; mt++) {
                floatx4 s_acc[4];
#pragma unroll
                for (int nt = 0; nt < 4; nt++) {
                    int krow = nt * 16 + l16;
                    const short8* kb0 = (const short8*)&Ks[buf][krow * 64 + ((quad       ^ (l16 & 7)) * 8)];
                    const short8* kb1 = (const short8*)&Ks[buf][krow * 64 + (((4 + quad) ^ (l16 & 7)) * 8)];
                    floatx4 z = {0.f, 0.f, 0.f, 0.f};
                    z = __builtin_amdgcn_mfma_f32_16x16x32_bf16(qa[mt][0], *kb0, z, 0, 0, 0);
                    s_acc[nt] = __builtin_amdgcn_mfma_f32_16x16x32_bf16(qa[mt][1], *kb1, z, 0, 0, 0);
                }
                int base_mt = qrow_base + mt * 16;
                if (s0 + 63 > base_mt) {
#pragma unroll
                    for (int nt = 0; nt < 4; nt++)
#pragma unroll
                        for (int r = 0; r < 4; r++) {
                            int gi = base_mt + quad * 4 + r;
                            int gj = s0 + nt * 16 + l16;
                            if (gj > gi) s_acc[nt][r] = -INFINITY;
                        }
                }
#pragma unroll
                for (int nt = 0; nt < 4; nt++)
#pragma unroll
                    for (int r = 0; r < 4; r++) {
                        float e = __expf(s_acc[nt][r]);
                        s_acc[nt][r] = e;
                        l_part[mt][r] += e;
                        Ps[wave][(mt * 16 + quad * 4 + r) * 72 + nt * 16 + l16] = f2bf(e);
                    }
            }
            asm volatile("s_waitcnt lgkmcnt(0)" ::: "memory");
            short8 pa[2][2];
#pragma unroll
            for (int mt = 0; mt < 2; mt++) {
                pa[mt][0] = *(const short8*)&Ps[wave][(mt * 16 + l16) * 72 + quad * 8];
                pa[mt][1] = *(const short8*)&Ps[wave][(mt * 16 + l16) * 72 + quad * 8 + 32];
            }
#pragma unroll
            for (int dt = 0; dt < 4; dt++) {
                int vrow = dt * 16 + l16;
                const short8* vb0 = (const short8*)&Vt[buf][vrow * 64 + ((quad       ^ (l16 & 7)) * 8)];
                const short8* vb1 = (const short8*)&Vt[buf][vrow * 64 + (((4 + quad) ^ (l16 & 7)) * 8)];
#pragma unroll
                for (int mt = 0; mt < 2; mt++) {
                    o_acc[mt][dt] = __builtin_amdgcn_mfma_f32_16x16x32_bf16(pa[mt][0], *vb0, o_acc[mt][dt], 0, 0, 0);
                    o_acc[mt][dt] = __builtin_amdgcn_mfma_f32_16x16x32_bf16(pa[mt][1], *vb1, o_acc[mt][dt], 0, 0, 0);
                }
            }
        }
    }

#pragma unroll
    for (int mt = 0; mt < 2; mt++)
#pragma unroll
        for (int r = 0; r < 4; r++) {
            float ls = l_part[mt][r];
            ls += __shfl_xor(ls, 1);
            ls += __shfl_xor(ls, 2);
            ls += __shfl_xor(ls, 4);
            ls += __shfl_xor(ls, 8);
            float inv = 1.f / ls;
            int gi = qrow_base + mt * 16 + quad * 4 + r;
            ushort* op = attnb + (size_t)(b * T_ + gi) * 1024 + h * 64;
#pragma unroll
            for (int dt = 0; dt < 4; dt++)
                op[dt * 16 + l16] = f2bf(o_acc[mt][dt][r] * inv);
        }
}

extern "C" void kernel_launch(void* const* d_in, const int* in_sizes, int n_in,
                              void* d_out, int out_size, void* d_ws, size_t ws_size,
                              hipStream_t stream) {
    (void)in_sizes; (void)n_in; (void)out_size; (void)ws_size;
    const float* x      = (const float*)d_in[0];
    const float* wq     = (const float*)d_in[1];
    const float* wk     = (const float*)d_in[2];
    const float* wv     = (const float*)d_in[3];
    const float* w_proj = (const float*)d_in[4];
    const float* b_proj = (const float*)d_in[5];
    const float* w1     = (const float*)d_in[6];
    const float* b1     = (const float*)d_in[7];
    const float* w2     = (const float*)d_in[8];
    const float* b2     = (const float*)d_in[9];
    const float* g1     = (const float*)d_in[10];
    const float* be1    = (const float*)d_in[11];
    const float* g2     = (const float*)d_in[12];
    const float* be2    = (const float*)d_in[13];
    float* out = (float*)d_out;

    char* ws = (char*)d_ws;
    const size_t MB = 1024ull * 1024ull;
    ushort* xn     = (ushort*)(ws + 0);        // 16 MB (reused as xn2 later)
    ushort* qkv    = (ushort*)(ws + 16 * MB);  // 48 MB
    ushort* attnb  = (ushort*)(ws + 64 * MB);  // 16 MB
    ushort* hbuf   = (ushort*)(ws + 16 * MB);  // 64 MB (aliases qkv+attnb, disjoint lifetime)
    float*  x1     = (float*) (ws + 80 * MB);  // 32 MB (written by proj, after attn)
    ushort* VtG    = (ushort*)(ws + 80 * MB);  // 16 MB (aliases x1; dead once proj runs)
    ushort* WqkvT  = (ushort*)(ws + 112 * MB); // 6 MB
    ushort* WprojT = (ushort*)(ws + 118 * MB); // 2 MB
    ushort* W1T    = (ushort*)(ws + 120 * MB); // 8 MB
    ushort* W2T    = (ushort*)(ws + 128 * MB); // 8 MB
    ushort* xn2 = xn;

    dim3 tb(32, 8);
    ln_kernel<<<M_, 256, 0, stream>>>(x, g1, be1, xn);
    transpose_conv<<<dim3(D_ / 32, C_ / 32, H_), tb, 0, stream>>>(wq, WqkvT,               C_, D_, (long long)C_ * D_, (long long)D_ * C_);
    transpose_conv<<<dim3(D_ / 32, C_ / 32, H_), tb, 0, stream>>>(wk, WqkvT + C_ * C_,     C_, D_, (long long)C_ * D_, (long long)D_ * C_);
    transpose_conv<<<dim3(D_ / 32, C_ / 32, H_), tb, 0, stream>>>(wv, WqkvT + 2 * C_ * C_, C_, D_, (long long)C_ * D_, (long long)D_ * C_);
    transpose_conv<<<dim3(C_ / 32, C_ / 32, 1), tb, 0, stream>>>(w_proj, WprojT, C_, C_, 0, 0);
    transpose_conv<<<dim3(4 * C_ / 32, C_ / 32, 1), tb, 0, stream>>>(w1, W1T, C_, 4 * C_, 0, 0);
    transpose_conv<<<dim3(C_ / 32, 4 * C_ / 32, 1), tb, 0, stream>>>(w2, W2T, 4 * C_, C_, 0, 0);
    // QKV: Mt=64, Nt=24
    gemm_kernel<true, false, false, false><<<64 * 24, 256, 0, stream>>>(
        xn, WqkvT, nullptr, nullptr, qkv, 3072, C_, 24);
    vtrans_kernel<<<dim3(T_ / 64, B_ * H_), 256, 0, stream>>>(qkv, VtG);
    attn_kernel<<<1024, 256, 0, stream>>>(qkv, VtG, attnb);
    // proj: Nt=8
    gemm_kernel<false, true, false, true><<<64 * 8, 256, 0, stream>>>(
        attnb, WprojT, b_proj, x, x1, C_, C_, 8);
    ln_kernel<<<M_, 256, 0, stream>>>(x1, g2, be2, xn2);
    // FFN1: Nt=32
    gemm_kernel<true, true, true, false><<<64 * 32, 256, 0, stream>>>(
        xn2, W1T, b1, nullptr, hbuf, 4 * C_, C_, 32);
    // FFN2: Nt=8
    gemm_kernel<false, true, false, true><<<64 * 8, 256, 0, stream>>>(
        hbuf, W2T, b2, x1, out, C_, 4 * C_, 8);
}

// Round 6
// 465.788 us; speedup vs baseline: 1.0111x; 1.0111x over previous
//
#include <hip/hip_runtime.h>
#include <hip/hip_bf16.h>

#define B_ 4
#define T_ 2048
#define C_ 1024
#define H_ 16
#define D_ 64
#define M_ (B_*T_)   // 8192

typedef unsigned short ushort;
typedef __attribute__((ext_vector_type(8))) short short8;
typedef __attribute__((ext_vector_type(8))) unsigned short ushort8;
typedef __attribute__((ext_vector_type(4))) float floatx4;
typedef __attribute__((ext_vector_type(4))) unsigned int uintx4;

static __device__ __forceinline__ float bf2f(ushort u) {
    unsigned int x = ((unsigned int)u) << 16;
    return __builtin_bit_cast(float, x);
}
static __device__ __forceinline__ ushort f2bf(float f) {
    unsigned int x = __builtin_bit_cast(unsigned int, f);
    unsigned int r = (x + 0x7fffu + ((x >> 16) & 1u)) >> 16;
    return (ushort)r;
}

typedef const __attribute__((address_space(1))) unsigned int gu32;
typedef __attribute__((address_space(3))) unsigned int lu32;
static __device__ __forceinline__ void glds16(const void* g, void* l) {
    __builtin_amdgcn_global_load_lds((gu32*)g, (lu32*)l, 16, 0, 0);
}

// ---------------- LayerNorm: fp32 in -> bf16 out ----------------
__global__ __launch_bounds__(256) void ln_kernel(
    const float* __restrict__ x, const float* __restrict__ g,
    const float* __restrict__ be, ushort* __restrict__ out)
{
    int row = blockIdx.x;
    int tid = threadIdx.x;
    const float* xr = x + (size_t)row * C_;
    float v[4];
    float s = 0.f, s2 = 0.f;
#pragma unroll
    for (int i = 0; i < 4; i++) {
        float t = xr[tid + i * 256];
        v[i] = t; s += t; s2 += t * t;
    }
#pragma unroll
    for (int off = 32; off; off >>= 1) {
        s  += __shfl_down(s, off);
        s2 += __shfl_down(s2, off);
    }
    __shared__ float rs[4], rs2[4];
    __shared__ float smu, srstd;
    int w = tid >> 6;
    if ((tid & 63) == 0) { rs[w] = s; rs2[w] = s2; }
    __syncthreads();
    if (tid == 0) {
        float ts  = rs[0] + rs[1] + rs[2] + rs[3];
        float ts2 = rs2[0] + rs2[1] + rs2[2] + rs2[3];
        float mu  = ts * (1.f / C_);
        float var = ts2 * (1.f / C_) - mu * mu;
        smu = mu; srstd = rsqrtf(var + 1e-5f);
    }
    __syncthreads();
    float mu = smu, r = srstd;
#pragma unroll
    for (int i = 0; i < 4; i++) {
        int c = tid + i * 256;
        out[(size_t)row * C_ + c] = f2bf((v[i] - mu) * r * g[c] + be[c]);
    }
}

// ------------- fused weight transpose+convert: all 6 jobs in one launch -------------
static __device__ __forceinline__ void do_transpose(
    const float* __restrict__ in, ushort* __restrict__ out,
    int R, int Cn, int bx, int by)
{
    __shared__ float tile[32][33];
    int tx = threadIdx.x;          // 32
    int ty = threadIdx.y;          // 8
    int c0 = bx * 32, r0 = by * 32;
#pragma unroll
    for (int i = 0; i < 32; i += 8) {
        tile[ty + i][tx] = in[(size_t)(r0 + ty + i) * Cn + c0 + tx];
    }
    __syncthreads();
#pragma unroll
    for (int i = 0; i < 32; i += 8) {
        int oc = c0 + ty + i;
        int orr = r0 + tx;
        out[(size_t)oc * R + orr] = f2bf(tile[tx][ty + i]);
    }
}

// job table: [0,3072) wq/wk/wv (1024 each), [3072,4096) w_proj, [4096,8192) w1, [8192,12288) w2
__global__ __launch_bounds__(256) void wt_fused_kernel(
    const float* __restrict__ wq, const float* __restrict__ wk, const float* __restrict__ wv,
    const float* __restrict__ w_proj, const float* __restrict__ w1, const float* __restrict__ w2,
    ushort* __restrict__ WqkvT, ushort* __restrict__ WprojT,
    ushort* __restrict__ W1T, ushort* __restrict__ W2T)
{
    int id = blockIdx.x;
    if (id < 3072) {
        int which = id >> 10;             // 0=q,1=k,2=v
        int lid = id & 1023;
        int bz = lid >> 6;                // head
        int rem = lid & 63;
        int by = rem >> 1, bx = rem & 1;
        const float* in = (which == 0 ? wq : which == 1 ? wk : wv) + (size_t)bz * C_ * D_;
        ushort* out = WqkvT + (size_t)which * C_ * C_ + (size_t)bz * D_ * C_;
        do_transpose(in, out, C_, D_, bx, by);
    } else if (id < 4096) {
        int lid = id - 3072;
        do_transpose(w_proj, WprojT, C_, C_, lid & 31, lid >> 5);
    } else if (id < 8192) {
        int lid = id - 4096;
        do_transpose(w1, W1T, C_, 4 * C_, lid & 127, lid >> 7);
    } else {
        int lid = id - 8192;
        do_transpose(w2, W2T, 4 * C_, C_, lid & 31, lid >> 5);
    }
}

// ------------- V transpose: qkv V block -> VtG[(h*256 + 4*d + b)*2048 + t] -------------
__global__ __launch_bounds__(256) void vtrans_kernel(
    const ushort* __restrict__ qkv, ushort* __restrict__ VtG)
{
    int bh = blockIdx.y;
    int b = bh >> 4, h = bh & 15;
    int j0 = blockIdx.x * 64;
    int tid = threadIdx.x;
    __shared__ unsigned int X[64 * 33];
    const ushort* Vg = qkv + (size_t)(b * T_) * 3072 + 2048 + h * 64;
#pragma unroll
    for (int it = 0; it < 2; it++) {
        int j = (tid >> 3) + it * 32;
        int dp = (tid & 7) * 4;
        uintx4 val = *(const uintx4*)(Vg + (size_t)(j0 + j) * 3072 + dp * 2);
#pragma unroll
        for (int k = 0; k < 4; k++) X[j * 33 + dp + k] = val[k];
    }
    __syncthreads();
    int dp = tid >> 3, jc = tid & 7;
    unsigned int v[8];
#pragma unroll
    for (int jj = 0; jj < 8; jj++) v[jj] = X[(jc * 8 + jj) * 33 + dp];
    ushort8 lo, hi;
#pragma unroll
    for (int jj = 0; jj < 8; jj++) {
        lo[jj] = (ushort)(v[jj] & 0xffffu);
        hi[jj] = (ushort)(v[jj] >> 16);
    }
    size_t r0 = ((size_t)(h * 256 + 4 * (2 * dp) + b)) * T_ + j0 + jc * 8;
    size_t r1 = ((size_t)(h * 256 + 4 * (2 * dp + 1) + b)) * T_ + j0 + jc * 8;
    *(ushort8*)&VtG[r0] = lo;
    *(ushort8*)&VtG[r1] = hi;
}

// ---------------- bf16 MFMA GEMM ----------------
// C(MxN) = A(MxK) @ Bt(NxK)^T [+bias][+resid][relu].
// 1D grid, XCD swizzle: xcd=bid&7, m fastest within slab (B-col reuse, A-slab 2MB in L2).
// DBUF: double-buffer + 1 barrier/K-step (for grid-limited dispatches, 2 blocks/CU);
// !DBUF: single buffer 32KB, 5 blocks/CU implicit wave overlap (for 6-8 blocks/CU grids).
template<bool OUTBF16, bool BIAS, bool RELU, bool RESID, bool DBUF>
__global__ __launch_bounds__(256, 2) void gemm_kernel(
    const ushort* __restrict__ A,
    const ushort* __restrict__ Bt,
    const float* __restrict__ bias,
    const float* __restrict__ resid,
    void* __restrict__ Cout,
    int Ndim, int K, int Nt)
{
    constexpr int NB = DBUF ? 2 : 1;
    __shared__ ushort As[NB][128 * 64];
    __shared__ ushort Bs[NB][128 * 64];
    int bid = blockIdx.x;
    int xcd = bid & 7;
    int loc = bid >> 3;
    int m0 = (xcd * 8 + (loc & 7)) * 128;   // m fastest: 8 consecutive blocks share a B-col
    int n0 = (loc >> 3) * 128;

    int tid = threadIdx.x;
    int wave = tid >> 6, lane = tid & 63;
    int quad = lane >> 4, l16 = lane & 15;
    int wm = (wave >> 1) * 64, wn = (wave & 1) * 64;
    floatx4 acc[4][4] = {};

    int lrow = lane >> 3;
    int lchunk = (lane & 7) ^ (lrow & 7);
    const ushort* Ab = A  + (size_t)m0 * K + lchunk * 8;
    const ushort* Bb = Bt + (size_t)n0 * K + lchunk * 8;

    int nK = K >> 6;
    if (DBUF) {
#pragma unroll
        for (int it = 0; it < 4; it++) {
            int rb = wave * 32 + it * 8;
            int r  = rb + lrow;
            glds16(Ab + (size_t)r * K, &As[0][rb * 64]);
            glds16(Bb + (size_t)r * K, &Bs[0][rb * 64]);
        }
    }

    for (int ki = 0; ki < nK; ki++) {
        int buf = DBUF ? (ki & 1) : 0;
        __syncthreads();
        if (DBUF) {
            if (ki + 1 < nK) {
                int kn = (ki + 1) * 64;
#pragma unroll
                for (int it = 0; it < 4; it++) {
                    int rb = wave * 32 + it * 8;
                    int r  = rb + lrow;
                    glds16(Ab + (size_t)r * K + kn, &As[buf ^ 1][rb * 64]);
                    glds16(Bb + (size_t)r * K + kn, &Bs[buf ^ 1][rb * 64]);
                }
            }
        } else {
            int kn = ki * 64;
#pragma unroll
            for (int it = 0; it < 4; it++) {
                int rb = wave * 32 + it * 8;
                int r  = rb + lrow;
                glds16(Ab + (size_t)r * K + kn, &As[0][rb * 64]);
                glds16(Bb + (size_t)r * K + kn, &Bs[0][rb * 64]);
            }
            __syncthreads();
        }
#pragma unroll
        for (int kk = 0; kk < 2; kk++) {
            short8 af[4], bfv[4];
            int c = kk * 4 + quad;
            int sw = (c ^ (l16 & 7)) * 8;
#pragma unroll
            for (int mi = 0; mi < 4; mi++)
                af[mi] = *(const short8*)&As[buf][(wm + mi * 16 + l16) * 64 + sw];
#pragma unroll
            for (int ni = 0; ni < 4; ni++)
                bfv[ni] = *(const short8*)&Bs[buf][(wn + ni * 16 + l16) * 64 + sw];
#pragma unroll
            for (int mi = 0; mi < 4; mi++)
#pragma unroll
                for (int ni = 0; ni < 4; ni++)
                    acc[mi][ni] = __builtin_amdgcn_mfma_f32_16x16x32_bf16(af[mi], bfv[ni], acc[mi][ni], 0, 0, 0);
        }
    }

    int r4 = quad * 4;
#pragma unroll
    for (int mi = 0; mi < 4; mi++) {
#pragma unroll
        for (int ni = 0; ni < 4; ni++) {
#pragma unroll
            for (int r = 0; r < 4; r++) {
                int gm = m0 + wm + mi * 16 + r4 + r;
                int gn = n0 + wn + ni * 16 + l16;
                float v = acc[mi][ni][r];
                if (BIAS)  v += bias[gn];
                if (RESID) v += resid[(size_t)gm * Ndim + gn];
                if (RELU)  v = fmaxf(v, 0.f);
                if (OUTBF16) ((ushort*)Cout)[(size_t)gm * Ndim + gn] = f2bf(v);
                else         ((float*)Cout)[(size_t)gm * Ndim + gn] = v;
            }
        }
    }
}

// ---------------- causal flash attention (unchanged from round 4/5) ----------------
__global__ __launch_bounds__(256, 2) void attn_kernel(
    const ushort* __restrict__ qkv,
    const ushort* __restrict__ VtG,
    ushort* __restrict__ attnb)
{
    const int LD = 3072;
    int bid = blockIdx.x;
    int bh = (bid & 7) * 8 + ((bid >> 3) & 7);
    int qt = 15 - (bid >> 6);
    int b = bh >> 4, h = bh & 15;
    int t0 = qt * 128;
    int tid = threadIdx.x;
    int wave = tid >> 6, lane = tid & 63;
    int quad = lane >> 4, l16 = lane & 15;

    __shared__ ushort Ks[2][64 * 64];
    __shared__ ushort Vt[2][64 * 64];
    __shared__ ushort Ps[4][32 * 72];

    const ushort* Qg = qkv + (size_t)(b * T_) * LD + h * 64;
    const ushort* Kg = Qg + 1024;
    const ushort* VtB = VtG + (size_t)(h * 256 + b) * T_;

    int qrow_base = t0 + wave * 32;
    int lrow = lane >> 3;
    int lchunk = (lane & 7) ^ (lrow & 7);

    short8 qa[2][2];
#pragma unroll
    for (int mt = 0; mt < 2; mt++) {
        const ushort* qp = Qg + (size_t)(qrow_base + mt * 16 + l16) * LD + quad * 8;
        ushort8 q0 = *(const ushort8*)qp;
        ushort8 q1 = *(const ushort8*)(qp + 32);
        ushort8 a0, a1;
#pragma unroll
        for (int d = 0; d < 8; d++) {
            a0[d] = f2bf(bf2f(q0[d]) * 0.03125f);
            a1[d] = f2bf(bf2f(q1[d]) * 0.03125f);
        }
        qa[mt][0] = __builtin_bit_cast(short8, a0);
        qa[mt][1] = __builtin_bit_cast(short8, a1);
    }

    float l_part[2][4];
    floatx4 o_acc[2][4];
#pragma unroll
    for (int mt = 0; mt < 2; mt++)
#pragma unroll
        for (int r = 0; r < 4; r++) {
            l_part[mt][r] = 0.f;
            o_acc[mt][r] = floatx4{0.f, 0.f, 0.f, 0.f};
        }

    int nIter = t0 / 64 + 2;

#pragma unroll
    for (int it = 0; it < 2; it++) {
        int rb = (wave * 2 + it) * 8;
        int r = rb + lrow;
        glds16(Kg  + (size_t)r * LD + lchunk * 8, &Ks[0][rb * 64]);
        glds16(VtB + (size_t)r * (4 * T_) + lchunk * 8, &Vt[0][rb * 64]);
    }

    for (int ii = 0; ii < nIter; ii++) {
        int s0 = ii * 64;
        int buf = ii & 1;
        __syncthreads();
        if (ii + 1 < nIter) {
            int sn = s0 + 64;
#pragma unroll
            for (int it = 0; it < 2; it++) {
                int rb = (wave * 2 + it) * 8;
                int r = rb + lrow;
                glds16(Kg  + (size_t)(sn + r) * LD + lchunk * 8, &Ks[buf ^ 1][rb * 64]);
                glds16(VtB + (size_t)r * (4 * T_) + sn + lchunk * 8, &Vt[buf ^ 1][rb * 64]);
            }
        }

        if (s0 <= qrow_base + 31) {
#pragma unroll
            for (int mt = 0; mt < 2; mt++) {
                floatx4 s_acc[4];
#pragma unroll
                for (int nt = 0; nt < 4; nt++) {
                    int krow = nt * 16 + l16;
                    const short8* kb0 = (const short8*)&Ks[buf][krow * 64 + ((quad       ^ (l16 & 7)) * 8)];
                    const short8* kb1 = (const short8*)&Ks[buf][krow * 64 + (((4 + quad) ^ (l16 & 7)) * 8)];
                    floatx4 z = {0.f, 0.f, 0.f, 0.f};
                    z = __builtin_amdgcn_mfma_f32_16x16x32_bf16(qa[mt][0], *kb0, z, 0, 0, 0);
                    s_acc[nt] = __builtin_amdgcn_mfma_f32_16x16x32_bf16(qa[mt][1], *kb1, z, 0, 0, 0);
                }
                int base_mt = qrow_base + mt * 16;
                if (s0 + 63 > base_mt) {
#pragma unroll
                    for (int nt = 0; nt < 4; nt++)
#pragma unroll
                        for (int r = 0; r < 4; r++) {
                            int gi = base_mt + quad * 4 + r;
                            int gj = s0 + nt * 16 + l16;
                            if (gj > gi) s_acc[nt][r] = -INFINITY;
                        }
                }
#pragma unroll
                for (int nt = 0; nt < 4; nt++)
#pragma unroll
                    for (int r = 0; r < 4; r++) {
                        float e = __expf(s_acc[nt][r]);
                        s_acc[nt][r] = e;
                        l_part[mt][r] += e;
                        Ps[wave][(mt * 16 + quad * 4 + r) * 72 + nt * 16 + l16] = f2bf(e);
                    }
            }
            asm volatile("s_waitcnt lgkmcnt(0)" ::: "memory");
            short8 pa[2][2];
#pragma unroll
            for (int mt = 0; mt < 2; mt++) {
                pa[mt][0] = *(const short8*)&Ps[wave][(mt * 16 + l16) * 72 + quad * 8];
                pa[mt][1] = *(const short8*)&Ps[wave][(mt * 16 + l16) * 72 + quad * 8 + 32];
            }
#pragma unroll
            for (int dt = 0; dt < 4; dt++) {
                int vrow = dt * 16 + l16;
                const short8* vb0 = (const short8*)&Vt[buf][vrow * 64 + ((quad       ^ (l16 & 7)) * 8)];
                const short8* vb1 = (const short8*)&Vt[buf][vrow * 64 + (((4 + quad) ^ (l16 & 7)) * 8)];
#pragma unroll
                for (int mt = 0; mt < 2; mt++) {
                    o_acc[mt][dt] = __builtin_amdgcn_mfma_f32_16x16x32_bf16(pa[mt][0], *vb0, o_acc[mt][dt], 0, 0, 0);
                    o_acc[mt][dt] = __builtin_amdgcn_mfma_f32_16x16x32_bf16(pa[mt][1], *vb1, o_acc[mt][dt], 0, 0, 0);
                }
            }
        }
    }

#pragma unroll
    for (int mt = 0; mt < 2; mt++)
#pragma unroll
        for (int r = 0; r < 4; r++) {
            float ls = l_part[mt][r];
            ls += __shfl_xor(ls, 1);
            ls += __shfl_xor(ls, 2);
            ls += __shfl_xor(ls, 4);
            ls += __shfl_xor(ls, 8);
            float inv = 1.f / ls;
            int gi = qrow_base + mt * 16 + quad * 4 + r;
            ushort* op = attnb + (size_t)(b * T_ + gi) * 1024 + h * 64;
#pragma unroll
            for (int dt = 0; dt < 4; dt++)
                op[dt * 16 + l16] = f2bf(o_acc[mt][dt][r] * inv);
        }
}

extern "C" void kernel_launch(void* const* d_in, const int* in_sizes, int n_in,
                              void* d_out, int out_size, void* d_ws, size_t ws_size,
                              hipStream_t stream) {
    (void)in_sizes; (void)n_in; (void)out_size; (void)ws_size;
    const float* x      = (const float*)d_in[0];
    const float* wq     = (const float*)d_in[1];
    const float* wk     = (const float*)d_in[2];
    const float* wv     = (const float*)d_in[3];
    const float* w_proj = (const float*)d_in[4];
    const float* b_proj = (const float*)d_in[5];
    const float* w1     = (const float*)d_in[6];
    const float* b1     = (const float*)d_in[7];
    const float* w2     = (const float*)d_in[8];
    const float* b2     = (const float*)d_in[9];
    const float* g1     = (const float*)d_in[10];
    const float* be1    = (const float*)d_in[11];
    const float* g2     = (const float*)d_in[12];
    const float* be2    = (const float*)d_in[13];
    float* out = (float*)d_out;

    char* ws = (char*)d_ws;
    const size_t MB = 1024ull * 1024ull;
    ushort* xn     = (ushort*)(ws + 0);        // 16 MB (reused as xn2 later)
    ushort* qkv    = (ushort*)(ws + 16 * MB);  // 48 MB
    ushort* attnb  = (ushort*)(ws + 64 * MB);  // 16 MB
    ushort* hbuf   = (ushort*)(ws + 16 * MB);  // 64 MB (aliases qkv+attnb, disjoint lifetime)
    float*  x1     = (float*) (ws + 80 * MB);  // 32 MB (written by proj, after attn)
    ushort* VtG    = (ushort*)(ws + 80 * MB);  // 16 MB (aliases x1; dead once proj runs)
    ushort* WqkvT  = (ushort*)(ws + 112 * MB); // 6 MB
    ushort* WprojT = (ushort*)(ws + 118 * MB); // 2 MB
    ushort* W1T    = (ushort*)(ws + 120 * MB); // 8 MB
    ushort* W2T    = (ushort*)(ws + 128 * MB); // 8 MB
    ushort* xn2 = xn;

    ln_kernel<<<M_, 256, 0, stream>>>(x, g1, be1, xn);
    wt_fused_kernel<<<12288, dim3(32, 8), 0, stream>>>(
        wq, wk, wv, w_proj, w1, w2, WqkvT, WprojT, W1T, W2T);
    // QKV: Nt=24, grid 1536 (6 blocks/CU) -> single-buffer
    gemm_kernel<true, false, false, false, false><<<64 * 24, 256, 0, stream>>>(
        xn, WqkvT, nullptr, nullptr, qkv, 3072, C_, 24);
    vtrans_kernel<<<dim3(T_ / 64, B_ * H_), 256, 0, stream>>>(qkv, VtG);
    attn_kernel<<<1024, 256, 0, stream>>>(qkv, VtG, attnb);
    // proj: Nt=8, grid 512 (2 blocks/CU) -> dbuf
    gemm_kernel<false, true, false, true, true><<<64 * 8, 256, 0, stream>>>(
        attnb, WprojT, b_proj, x, x1, C_, C_, 8);
    ln_kernel<<<M_, 256, 0, stream>>>(x1, g2, be2, xn2);
    // FFN1: Nt=32, grid 2048 (8 blocks/CU) -> single-buffer
    gemm_kernel<true, true, true, false, false><<<64 * 32, 256, 0, stream>>>(
        xn2, W1T, b1, nullptr, hbuf, 4 * C_, C_, 32);
    // FFN2: Nt=8, grid 512 (2 blocks/CU) -> dbuf
    gemm_kernel<false, true, false, true, true><<<64 * 8, 256, 0, stream>>>(
        hbuf, W2T, b2, x1, out, C_, 4 * C_, 8);
}